// Round 9
// baseline (54.417 us; speedup 1.0000x reference)
//
#include <hip/hip_runtime.h>
#include <math.h>

#define LL 2048
#define LSHIFT 11
#define LMASK 2047
#define NTOT (LL * LL)

typedef float f32x4 __attribute__((ext_vector_type(4)));
typedef float f32x2 __attribute__((ext_vector_type(2)));

#define TROWS 7     // rows i-3 .. i+3 (own stencil +-2, neighbor's stencil +-3)
#define TCOLS 528   // cols j0-8 .. j0+519 (512-cell block + halo)
#define CPB   512   // cells per block (2 per thread, cols t and t+256)

// d_profit = fl(fl(coop/5)*3.8).  For coop in 0..5, fl(coop/5) == coop*0.2f
// bit-exactly (verified case-by-case), so two mults replace the divide.
__device__ __forceinline__ float dprof(int coop) {
    return __fmul_rn(__fmul_rn((float)coop, 0.2f), 3.8f);
}

// plus-of-plus stencil profit for LDS cell (cr, cc); exact per-op f32
__device__ __forceinline__ float cell_profit(const int ty[TROWS][TCOLS],
                                             int cr, int cc, int& t00o) {
    int t00 = ty[cr][cc];
    int tW  = ty[cr][cc - 1], tE  = ty[cr][cc + 1];
    int tWW = ty[cr][cc - 2], tEE = ty[cr][cc + 2];
    int tN  = ty[cr - 1][cc], tNW = ty[cr - 1][cc - 1], tNE = ty[cr - 1][cc + 1];
    int tS  = ty[cr + 1][cc], tSW = ty[cr + 1][cc - 1], tSE = ty[cr + 1][cc + 1];
    int tNN = ty[cr - 2][cc], tSS = ty[cr + 2][cc];

    int coopC = t00 + tN + tS + tW + tE;
    int coopN = tN + tNN + t00 + tNW + tNE;
    int coopS = tS + t00 + tSS + tSW + tSE;
    int coopW = tW + tNW + tSW + tWW + t00;
    int coopE = tE + tNE + tSE + t00 + tEE;

    float dC = dprof(coopC), dN = dprof(coopN), dS = dprof(coopS),
          dW = dprof(coopW), dE = dprof(coopE);
    float cC = __fsub_rn(dC, 1.0f), cN = __fsub_rn(dN, 1.0f),
          cS = __fsub_rn(dS, 1.0f), cW = __fsub_rn(dW, 1.0f),
          cE = __fsub_rn(dE, 1.0f);
    // _neighbor5: ((((center + up) + down) + left) + right)
    float c5 = __fadd_rn(__fadd_rn(__fadd_rn(__fadd_rn(cC, cN), cS), cW), cE);
    float d5 = __fadd_rn(__fadd_rn(__fadd_rn(__fadd_rn(dC, dN), dS), dW), dE);
    t00o = t00;
    return t00 ? c5 : d5;
}

// greedy action + q_new chain, exact per-op f32 to match reference.
// tie is loaded LAZILY: masked = is_max - (1-is_max)*1e9 with tie in [0,1)
// means tie can only change the argmax when qa0 == qa1 exactly.
__device__ __forceinline__ void qstep(int A, f32x4 q, const f32x2* tie2, int n,
                                      float profit, float& qn, int& Bact) {
    float qa0 = A ? q.z : q.x;
    float qa1 = A ? q.w : q.y;
    int greedy;
    if (qa0 == qa1) {                 // rare: exact tie -> tie_rand decides
        f32x2 tr = tie2[n];
        float v0 = __fadd_rn(1.0f, tr.x);
        float v1 = __fadd_rn(1.0f, tr.y);
        greedy = (v1 > v0) ? 1 : 0;
    } else {
        greedy = (qa1 > qa0) ? 1 : 0; // mask -1e9 loses regardless of tie
    }
    int B = greedy;                   // EPSILON=-1 -> eps_mask always true
    float qb0 = B ? q.z : q.x;
    float qb1 = B ? q.w : q.y;
    float mn = fmaxf(qb0, qb1);       // max_a' Q_old[n, B, a']
    float qold = A ? (B ? q.w : q.z) : (B ? q.y : q.x);
    float a1 = __fmul_rn(0.8f, mn);
    float a2 = __fadd_rn(profit, a1);
    float a3 = __fsub_rn(a2, qold);
    float a4 = __fmul_rn(0.8f, a3);
    qn = __fadd_rn(qold, a4);
    Bact = B;
}

// fermi + output writes for one cell
__device__ __forceinline__ void do_cell(const int ty[TROWS][TCOLS], int jc,
                                        int drow, int dcol, int n, int nn,
                                        f32x4 q, f32x4 qn4, float l,
                                        const f32x2* tie2, float* outT,
                                        float* outQ, float* outP) {
    int t00;
    float profitC = cell_profit(ty, 3, jc, t00);
    float qnC; int BC;
    qstep(t00, q, tie2, n, profitC, qnC, BC);

    int tn0;
    float profitN = cell_profit(ty, 3 + drow, jc + dcol, tn0);
    float qnN; int BN;
    qstep(tn0, qn4, tie2, nn, profitN, qnN, BN);

    // W = sigmoid((pn-pc)/0.5).  Fast f32 path; |W32 - W_f64| < ~3e-6, so a
    // 1e-4 guard band around lp makes the decision provably identical to the
    // f64 formulation; only guard-band lanes take the slow f64 exp.
    float z32 = __fmul_rn(__fsub_rn(qnC, qnN), 2.0f);
    float W32 = 1.0f / (1.0f + __expf(z32));
    int take;
    if (fabsf(l - W32) > 1.0e-4f) {
        take = (l <= W32);
    } else {
        double W = 1.0 / (1.0 + exp(((double)qnC - (double)qnN) * 2.0));
        take = ((double)l <= W);
    }
    int tsel = take ? BN : t00;

    f32x4 qo = q;
    if (t00 == 0) { if (BC == 0) qo.x = qnC; else qo.y = qnC; }
    else          { if (BC == 0) qo.z = qnC; else qo.w = qnC; }

    __builtin_nontemporal_store(qo, (f32x4*)outQ + n);
    __builtin_nontemporal_store(profitC, outP + n);
    __builtin_nontemporal_store((float)tsel, outT + n);
}

// ---------- fused kernel: 2 cells/thread, same row, cols t and t+256 ----------
// Round-6 structure; each thread carries two INDEPENDENT dir->Q[nn] chains
// issued back-to-back (2x MLP on the serial latency path), and staging /
// addressing is amortized over 2 cells.  All streams lane-coalesced.

__global__ __launch_bounds__(256) void k_fused(
    const int* __restrict__ type, const float* __restrict__ Q,
    const float* __restrict__ tie, const int* __restrict__ dir,
    const float* __restrict__ lp, float* __restrict__ outT,
    float* __restrict__ outQ, float* __restrict__ outP)
{
    __shared__ int ty[TROWS][TCOLS];            // 14.4 KB -> 8 blocks/CU ok
    int bi = blockIdx.x;
    int i  = bi >> 2;                           // row
    int j0 = (bi & 3) << 9;                     // col base (0,512,1024,1536)
    int t  = threadIdx.x;
    int n1 = (i << LSHIFT) | (j0 + t);
    int n2 = n1 + 256;

    // independent streaming loads first; latency hides under staging
    int   d1 = dir[n1], d2 = dir[n2];
    float l1 = lp[n1],  l2 = lp[n2];
    const f32x4* Q4 = (const f32x4*)Q;
    f32x4 qA = Q4[n1], qB = Q4[n2];

    // stage 7 rows x 132 int4 of the type halo, coalesced
    const int4* T4 = (const int4*)type;
    for (int ll = t; ll < 132 * TROWS; ll += 256) {
        int rr = ll / 132;
        int cidx = ll - rr * 132;
        int r = (i - 3 + rr) & LMASK;
        int c = (j0 - 8 + (cidx << 2)) & LMASK;
        *(int4*)&ty[rr][cidx << 2] = T4[((r << LSHIFT) | c) >> 2];
    }

    // selected neighbors (rolls: 0 left, 1 right, 2 up, 3 down) — both
    // gathers issued together: two chains in flight per thread
    int drow1 = (d1 == 2) ? -1 : ((d1 == 3) ? 1 : 0);
    int dcol1 = (d1 == 0) ? -1 : ((d1 == 1) ? 1 : 0);
    int nn1 = (((i + drow1) & LMASK) << LSHIFT) | ((j0 + t + dcol1) & LMASK);
    int drow2 = (d2 == 2) ? -1 : ((d2 == 3) ? 1 : 0);
    int dcol2 = (d2 == 0) ? -1 : ((d2 == 1) ? 1 : 0);
    int nn2 = (((i + drow2) & LMASK) << LSHIFT) | ((j0 + t + 256 + dcol2) & LMASK);
    f32x4 qn4_1 = Q4[nn1];
    f32x4 qn4_2 = Q4[nn2];

    __syncthreads();

    const f32x2* tie2 = (const f32x2*)tie;
    do_cell(ty, t + 8,       drow1, dcol1, n1, nn1, qA, qn4_1, l1,
            tie2, outT, outQ, outP);
    do_cell(ty, t + 8 + 256, drow2, dcol2, n2, nn2, qB, qn4_2, l2,
            tie2, outT, outQ, outP);
}

// ---------- host ----------

extern "C" void kernel_launch(void* const* d_in, const int* in_sizes, int n_in,
                              void* d_out, int out_size, void* d_ws, size_t ws_size,
                              hipStream_t stream) {
    const int*   type = (const int*)d_in[0];
    const float* Q    = (const float*)d_in[1];
    const float* tie  = (const float*)d_in[2];
    // d_in[3] random_type and d_in[4] eps_rand are dead: eps_rand >= -1 always
    const int*   dir  = (const int*)d_in[5];
    const float* lp   = (const float*)d_in[6];

    float* out  = (float*)d_out;
    float* outT = out;                       // [N]  type_t2
    float* outQ = out + (size_t)NTOT;        // [4N] Q_new
    float* outP = out + (size_t)NTOT * 5;    // [N]  profit

    dim3 blk(256), grd(NTOT / CPB);
    hipLaunchKernelGGL(k_fused, grd, blk, 0, stream,
                       type, Q, tie, dir, lp, outT, outQ, outP);
}

// Round 10
// 40.698 us; speedup vs baseline: 1.3371x; 1.3371x over previous
//
#include <hip/hip_runtime.h>
#include <math.h>

#define LL 2048
#define LSHIFT 11
#define LMASK 2047
#define NTOT (LL * LL)

typedef float f32x4 __attribute__((ext_vector_type(4)));
typedef float f32x2 __attribute__((ext_vector_type(2)));

#define TROWS 7     // rows i-3 .. i+3 (own stencil +-2, neighbor's stencil +-3)
#define WCOLS 72    // per-wave tile cols: j0w-4 .. j0w+67 (need j0w-3 .. j0w+66)
#define WINT4 (WCOLS / 4 * TROWS)   // 126 int4 per wave tile

// d_profit = fl(fl(coop/5)*3.8).  For coop in 0..5, fl(coop/5) == coop*0.2f
// bit-exactly (verified case-by-case), so two mults replace the divide.
__device__ __forceinline__ float dprof(int coop) {
    return __fmul_rn(__fmul_rn((float)coop, 0.2f), 3.8f);
}

// plus-of-plus stencil profit for wave-tile cell (cr, cc); exact per-op f32
__device__ __forceinline__ float cell_profit(const int ty[TROWS][WCOLS],
                                             int cr, int cc, int& t00o) {
    int t00 = ty[cr][cc];
    int tW  = ty[cr][cc - 1], tE  = ty[cr][cc + 1];
    int tWW = ty[cr][cc - 2], tEE = ty[cr][cc + 2];
    int tN  = ty[cr - 1][cc], tNW = ty[cr - 1][cc - 1], tNE = ty[cr - 1][cc + 1];
    int tS  = ty[cr + 1][cc], tSW = ty[cr + 1][cc - 1], tSE = ty[cr + 1][cc + 1];
    int tNN = ty[cr - 2][cc], tSS = ty[cr + 2][cc];

    int coopC = t00 + tN + tS + tW + tE;
    int coopN = tN + tNN + t00 + tNW + tNE;
    int coopS = tS + t00 + tSS + tSW + tSE;
    int coopW = tW + tNW + tSW + tWW + t00;
    int coopE = tE + tNE + tSE + t00 + tEE;

    float dC = dprof(coopC), dN = dprof(coopN), dS = dprof(coopS),
          dW = dprof(coopW), dE = dprof(coopE);
    float cC = __fsub_rn(dC, 1.0f), cN = __fsub_rn(dN, 1.0f),
          cS = __fsub_rn(dS, 1.0f), cW = __fsub_rn(dW, 1.0f),
          cE = __fsub_rn(dE, 1.0f);
    // _neighbor5: ((((center + up) + down) + left) + right)
    float c5 = __fadd_rn(__fadd_rn(__fadd_rn(__fadd_rn(cC, cN), cS), cW), cE);
    float d5 = __fadd_rn(__fadd_rn(__fadd_rn(__fadd_rn(dC, dN), dS), dW), dE);
    t00o = t00;
    return t00 ? c5 : d5;
}

// greedy action + q_new chain, exact per-op f32 to match reference.
// tie is loaded LAZILY: masked = is_max - (1-is_max)*1e9 with tie in [0,1)
// means tie can only change the argmax when qa0 == qa1 exactly.
__device__ __forceinline__ void qstep(int A, f32x4 q, const f32x2* tie2, int n,
                                      float profit, float& qn, int& Bact) {
    float qa0 = A ? q.z : q.x;
    float qa1 = A ? q.w : q.y;
    int greedy;
    if (qa0 == qa1) {                 // rare: exact tie -> tie_rand decides
        f32x2 tr = tie2[n];
        float v0 = __fadd_rn(1.0f, tr.x);
        float v1 = __fadd_rn(1.0f, tr.y);
        greedy = (v1 > v0) ? 1 : 0;
    } else {
        greedy = (qa1 > qa0) ? 1 : 0; // mask -1e9 loses regardless of tie
    }
    int B = greedy;                   // EPSILON=-1 -> eps_mask always true
    float qb0 = B ? q.z : q.x;
    float qb1 = B ? q.w : q.y;
    float mn = fmaxf(qb0, qb1);       // max_a' Q_old[n, B, a']
    float qold = A ? (B ? q.w : q.z) : (B ? q.y : q.x);
    float a1 = __fmul_rn(0.8f, mn);
    float a2 = __fadd_rn(profit, a1);
    float a3 = __fsub_rn(a2, qold);
    float a4 = __fmul_rn(0.8f, a3);
    qn = __fadd_rn(qold, a4);
    Bact = B;
}

// ---------- fused kernel: stencil + greedy + Q update + fermi ----------
// Round-6 structure (best: 40.2 us) with ONE change: staging is WAVE-PRIVATE.
// Each 64-lane wave stages its own 7x72 type tile into its own LDS region and
// fences with s_waitcnt lgkmcnt(0) only -- no __syncthreads, so the 4 waves
// of a block never couple; every wave is an independent pipeline.

__global__ __launch_bounds__(256, 8) void k_fused(
    const int* __restrict__ type, const float* __restrict__ Q,
    const float* __restrict__ tie, const int* __restrict__ dir,
    const float* __restrict__ lp, float* __restrict__ outT,
    float* __restrict__ outQ, float* __restrict__ outP)
{
    __shared__ int ty4[4][TROWS][WCOLS];        // 4 x 2.0 KB = 8.1 KB
    int bi   = blockIdx.x;
    int i    = bi >> 3;                         // row
    int j0   = (bi & 7) << 8;                   // block col base
    int t    = threadIdx.x;
    int w    = t >> 6;                          // wave id 0..3
    int lane = t & 63;
    int j0w  = j0 + (w << 6);                   // wave col base
    int j    = j0w + lane;
    int n    = (i << LSHIFT) | j;

    // own-cell streaming loads first; latency hides under staging
    int   d  = dir[n];
    float l  = lp[n];
    f32x4 q  = ((const f32x4*)Q)[n];

    // stage this wave's 7 x 18 int4 tile, coalesced, wave-private
    int (*ty)[WCOLS] = ty4[w];
    const int4* T4 = (const int4*)type;
    for (int ll = lane; ll < WINT4; ll += 64) {
        int rr = ll / 18;
        int cidx = ll - rr * 18;
        int r = (i - 3 + rr) & LMASK;
        int c = (j0w - 4 + (cidx << 2)) & LMASK;
        *(int4*)&ty[rr][cidx << 2] = T4[((r << LSHIFT) | c) >> 2];
    }

    // selected neighbor (rolls: 0 left, 1 right, 2 up, 3 down)
    int drow = (d == 2) ? -1 : ((d == 3) ? 1 : 0);
    int dcol = (d == 0) ? -1 : ((d == 1) ? 1 : 0);
    int nn = (((i + drow) & LMASK) << LSHIFT) | ((j + dcol) & LMASK);
    f32x4 qn4 = ((const f32x4*)Q)[nn];          // gather, L2/L3-hot

    // wave-local fence: all our ds_writes done; no inter-wave barrier
    asm volatile("s_waitcnt lgkmcnt(0)" ::: "memory");
    __builtin_amdgcn_sched_barrier(0);

    const f32x2* tie2 = (const f32x2*)tie;
    int jc = lane + 4;                          // own col in wave tile, row 3
    int t00;
    float profitC = cell_profit(ty, 3, jc, t00);
    float qnC; int BC;
    qstep(t00, q, tie2, n, profitC, qnC, BC);

    int tn0;
    float profitN = cell_profit(ty, 3 + drow, jc + dcol, tn0);
    float qnN; int BN;
    qstep(tn0, qn4, tie2, nn, profitN, qnN, BN);

    // W = sigmoid((pn-pc)/0.5).  Fast f32 path; |W32 - W_f64| < ~3e-6, so a
    // 1e-4 guard band around lp makes the decision provably identical to the
    // f64 formulation; only guard-band lanes take the slow f64 exp.
    float z32 = __fmul_rn(__fsub_rn(qnC, qnN), 2.0f);
    float W32 = 1.0f / (1.0f + __expf(z32));
    int take;
    if (fabsf(l - W32) > 1.0e-4f) {
        take = (l <= W32);
    } else {
        double W = 1.0 / (1.0 + exp(((double)qnC - (double)qnN) * 2.0));
        take = ((double)l <= W);
    }
    int tsel = take ? BN : t00;

    f32x4 qo = q;
    if (t00 == 0) { if (BC == 0) qo.x = qnC; else qo.y = qnC; }
    else          { if (BC == 0) qo.z = qnC; else qo.w = qnC; }

    __builtin_nontemporal_store(qo, (f32x4*)outQ + n);
    __builtin_nontemporal_store(profitC, outP + n);
    __builtin_nontemporal_store((float)tsel, outT + n);
}

// ---------- host ----------

extern "C" void kernel_launch(void* const* d_in, const int* in_sizes, int n_in,
                              void* d_out, int out_size, void* d_ws, size_t ws_size,
                              hipStream_t stream) {
    const int*   type = (const int*)d_in[0];
    const float* Q    = (const float*)d_in[1];
    const float* tie  = (const float*)d_in[2];
    // d_in[3] random_type and d_in[4] eps_rand are dead: eps_rand >= -1 always
    const int*   dir  = (const int*)d_in[5];
    const float* lp   = (const float*)d_in[6];

    float* out  = (float*)d_out;
    float* outT = out;                       // [N]  type_t2
    float* outQ = out + (size_t)NTOT;        // [4N] Q_new
    float* outP = out + (size_t)NTOT * 5;    // [N]  profit

    dim3 blk(256), grd(NTOT / 256);
    hipLaunchKernelGGL(k_fused, grd, blk, 0, stream,
                       type, Q, tie, dir, lp, outT, outQ, outP);
}

// Round 11
// 40.623 us; speedup vs baseline: 1.3396x; 1.0018x over previous
//
#include <hip/hip_runtime.h>
#include <math.h>

#define LL 2048
#define LSHIFT 11
#define LMASK 2047
#define NTOT (LL * LL)

typedef float f32x4 __attribute__((ext_vector_type(4)));
typedef float f32x2 __attribute__((ext_vector_type(2)));

#define TROWS 10    // rows 2r-3 .. 2r+4 (two cell rows, each needs +-3)
#define TCOLS 272   // cols j0-8 .. j0+263

// d_profit = fl(fl(coop/5)*3.8).  For coop in 0..5, fl(coop/5) == coop*0.2f
// bit-exactly (verified case-by-case), so two mults replace the divide.
__device__ __forceinline__ float dprof(int coop) {
    return __fmul_rn(__fmul_rn((float)coop, 0.2f), 3.8f);
}

// plus-of-plus stencil profit for LDS cell (cr, cc); exact per-op f32
__device__ __forceinline__ float cell_profit(const int ty[TROWS][TCOLS],
                                             int cr, int cc, int& t00o) {
    int t00 = ty[cr][cc];
    int tW  = ty[cr][cc - 1], tE  = ty[cr][cc + 1];
    int tWW = ty[cr][cc - 2], tEE = ty[cr][cc + 2];
    int tN  = ty[cr - 1][cc], tNW = ty[cr - 1][cc - 1], tNE = ty[cr - 1][cc + 1];
    int tS  = ty[cr + 1][cc], tSW = ty[cr + 1][cc - 1], tSE = ty[cr + 1][cc + 1];
    int tNN = ty[cr - 2][cc], tSS = ty[cr + 2][cc];

    int coopC = t00 + tN + tS + tW + tE;
    int coopN = tN + tNN + t00 + tNW + tNE;
    int coopS = tS + t00 + tSS + tSW + tSE;
    int coopW = tW + tNW + tSW + tWW + t00;
    int coopE = tE + tNE + tSE + t00 + tEE;

    float dC = dprof(coopC), dN = dprof(coopN), dS = dprof(coopS),
          dW = dprof(coopW), dE = dprof(coopE);
    float cC = __fsub_rn(dC, 1.0f), cN = __fsub_rn(dN, 1.0f),
          cS = __fsub_rn(dS, 1.0f), cW = __fsub_rn(dW, 1.0f),
          cE = __fsub_rn(dE, 1.0f);
    // _neighbor5: ((((center + up) + down) + left) + right)
    float c5 = __fadd_rn(__fadd_rn(__fadd_rn(__fadd_rn(cC, cN), cS), cW), cE);
    float d5 = __fadd_rn(__fadd_rn(__fadd_rn(__fadd_rn(dC, dN), dS), dW), dE);
    t00o = t00;
    return t00 ? c5 : d5;
}

// greedy action + q_new chain, exact per-op f32 to match reference.
// tie is loaded LAZILY: masked = is_max - (1-is_max)*1e9 with tie in [0,1)
// means tie can only change the argmax when qa0 == qa1 exactly.
__device__ __forceinline__ void qstep(int A, f32x4 q, const f32x2* tie2, int n,
                                      float profit, float& qn, int& Bact) {
    float qa0 = A ? q.z : q.x;
    float qa1 = A ? q.w : q.y;
    int greedy;
    if (qa0 == qa1) {                 // rare: exact tie -> tie_rand decides
        f32x2 tr = tie2[n];
        float v0 = __fadd_rn(1.0f, tr.x);
        float v1 = __fadd_rn(1.0f, tr.y);
        greedy = (v1 > v0) ? 1 : 0;
    } else {
        greedy = (qa1 > qa0) ? 1 : 0; // mask -1e9 loses regardless of tie
    }
    int B = greedy;                   // EPSILON=-1 -> eps_mask always true
    float qb0 = B ? q.z : q.x;
    float qb1 = B ? q.w : q.y;
    float mn = fmaxf(qb0, qb1);       // max_a' Q_old[n, B, a']
    float qold = A ? (B ? q.w : q.z) : (B ? q.y : q.x);
    float a1 = __fmul_rn(0.8f, mn);
    float a2 = __fadd_rn(profit, a1);
    float a3 = __fsub_rn(a2, qold);
    float a4 = __fmul_rn(0.8f, a3);
    qn = __fadd_rn(qold, a4);
    Bact = B;
}

// fermi + output writes for one cell; cr = LDS row of the cell
__device__ __forceinline__ void do_cell(const int ty[TROWS][TCOLS], int cr,
                                        int jc, int drow, int dcol, int n,
                                        int nn, f32x4 q, f32x4 qn4, float l,
                                        const f32x2* tie2, float* outT,
                                        float* outQ, float* outP) {
    int t00;
    float profitC = cell_profit(ty, cr, jc, t00);
    float qnC; int BC;
    qstep(t00, q, tie2, n, profitC, qnC, BC);

    int tn0;
    float profitN = cell_profit(ty, cr + drow, jc + dcol, tn0);
    float qnN; int BN;
    qstep(tn0, qn4, tie2, nn, profitN, qnN, BN);

    // W = sigmoid((pn-pc)/0.5).  Fast f32 path; |W32 - W_f64| < ~3e-6, so a
    // 1e-4 guard band around lp makes the decision provably identical to the
    // f64 formulation; only guard-band lanes take the slow f64 exp.
    float z32 = __fmul_rn(__fsub_rn(qnC, qnN), 2.0f);
    float W32 = 1.0f / (1.0f + __expf(z32));
    int take;
    if (fabsf(l - W32) > 1.0e-4f) {
        take = (l <= W32);
    } else {
        double W = 1.0 / (1.0 + exp(((double)qnC - (double)qnN) * 2.0));
        take = ((double)l <= W);
    }
    int tsel = take ? BN : t00;

    f32x4 qo = q;
    if (t00 == 0) { if (BC == 0) qo.x = qnC; else qo.y = qnC; }
    else          { if (BC == 0) qo.z = qnC; else qo.w = qnC; }

    __builtin_nontemporal_store(qo, (f32x4*)outQ + n);
    __builtin_nontemporal_store(profitC, outP + n);
    __builtin_nontemporal_store((float)tsel, outT + n);
}

// ---------- fused kernel: 2 cells/thread, ROW-PAIR geometry ----------
// Identical col-chunk geometry to round 6 (the 40.2us champion): 256-col
// chunks, lane<->column identity, same dispatch order.  Each thread owns
// (2r, j) and (2r+1, j): two fully independent dir->gather->compute->store
// pipelines issued back-to-back (2x MLP), staged from one shared 10-row halo
// (type redundancy per cell-row drops 7x -> 5x).

__global__ __launch_bounds__(256, 8) void k_fused(
    const int* __restrict__ type, const float* __restrict__ Q,
    const float* __restrict__ tie, const int* __restrict__ dir,
    const float* __restrict__ lp, float* __restrict__ outT,
    float* __restrict__ outQ, float* __restrict__ outP)
{
    __shared__ int ty[TROWS][TCOLS];            // 10.6 KB
    int bi = blockIdx.x;
    int i0 = (bi >> 3) << 1;                    // first row of the pair
    int j0 = (bi & 7) << 8;                     // col base
    int t  = threadIdx.x;
    int j  = j0 + t;
    int n1 = (i0 << LSHIFT) | j;
    int n2 = n1 + LL;                           // row i0+1, same column

    // independent streaming loads first; latency hides under staging
    int   d1 = dir[n1], d2 = dir[n2];
    float l1 = lp[n1],  l2 = lp[n2];
    const f32x4* Q4 = (const f32x4*)Q;
    f32x4 qA = Q4[n1], qB = Q4[n2];

    // stage 10 rows x 68 int4 of the type halo, coalesced
    const int4* T4 = (const int4*)type;
    for (int ll = t; ll < 68 * TROWS; ll += 256) {
        int rr = ll / 68;
        int cidx = ll - rr * 68;
        int r = (i0 - 3 + rr) & LMASK;
        int c = (j0 - 8 + (cidx << 2)) & LMASK;
        *(int4*)&ty[rr][cidx << 2] = T4[((r << LSHIFT) | c) >> 2];
    }

    // selected neighbors (rolls: 0 left, 1 right, 2 up, 3 down); both gathers
    // issued together -> two chains in flight per thread
    int drow1 = (d1 == 2) ? -1 : ((d1 == 3) ? 1 : 0);
    int dcol1 = (d1 == 0) ? -1 : ((d1 == 1) ? 1 : 0);
    int nn1 = (((i0 + drow1) & LMASK) << LSHIFT) | ((j + dcol1) & LMASK);
    int drow2 = (d2 == 2) ? -1 : ((d2 == 3) ? 1 : 0);
    int dcol2 = (d2 == 0) ? -1 : ((d2 == 1) ? 1 : 0);
    int nn2 = ((((i0 + 1) + drow2) & LMASK) << LSHIFT) | ((j + dcol2) & LMASK);
    f32x4 qn4_1 = Q4[nn1];
    f32x4 qn4_2 = Q4[nn2];

    __syncthreads();

    const f32x2* tie2 = (const f32x2*)tie;
    int jc = t + 8;
    // cell rows: i0 -> LDS row 3, i0+1 -> LDS row 4
    do_cell(ty, 3, jc, drow1, dcol1, n1, nn1, qA, qn4_1, l1,
            tie2, outT, outQ, outP);
    do_cell(ty, 4, jc, drow2, dcol2, n2, nn2, qB, qn4_2, l2,
            tie2, outT, outQ, outP);
}

// ---------- host ----------

extern "C" void kernel_launch(void* const* d_in, const int* in_sizes, int n_in,
                              void* d_out, int out_size, void* d_ws, size_t ws_size,
                              hipStream_t stream) {
    const int*   type = (const int*)d_in[0];
    const float* Q    = (const float*)d_in[1];
    const float* tie  = (const float*)d_in[2];
    // d_in[3] random_type and d_in[4] eps_rand are dead: eps_rand >= -1 always
    const int*   dir  = (const int*)d_in[5];
    const float* lp   = (const float*)d_in[6];

    float* out  = (float*)d_out;
    float* outT = out;                       // [N]  type_t2
    float* outQ = out + (size_t)NTOT;        // [4N] Q_new
    float* outP = out + (size_t)NTOT * 5;    // [N]  profit

    dim3 blk(256), grd(NTOT / 512);
    hipLaunchKernelGGL(k_fused, grd, blk, 0, stream,
                       type, Q, tie, dir, lp, outT, outQ, outP);
}